// Round 8
// baseline (1411.684 us; speedup 1.0000x reference)
//
#include <hip/hip_runtime.h>
#include <math.h>

typedef unsigned short u16;
typedef short s16x8 __attribute__((ext_vector_type(8)));
typedef float f32x16 __attribute__((ext_vector_type(16)));

#define GLOAD16(gp, lp)                                                        \
  __builtin_amdgcn_global_load_lds(                                            \
      (const __attribute__((address_space(1))) void*)(gp),                     \
      (__attribute__((address_space(3))) void*)(lp), 16, 0, 0)

__device__ __forceinline__ u16 f2bf(float f) {
  union { float f; unsigned u; } v; v.f = f;
  unsigned r = v.u + 0x7fffu + ((v.u >> 16) & 1u);  // RNE
  return (u16)(r >> 16);
}

// ---------------- kernel 1: x fp32 -> bf16 ----------------
__global__ __launch_bounds__(256) void cvt_x_kernel(const float* __restrict__ in,
                                                    u16* __restrict__ out) {
  size_t i = ((size_t)blockIdx.x * 256 + threadIdx.x) * 8;
  float4 a = *(const float4*)(in + i);
  float4 b = *(const float4*)(in + i + 4);
  s16x8 v;
  v[0] = (short)f2bf(a.x); v[1] = (short)f2bf(a.y);
  v[2] = (short)f2bf(a.z); v[3] = (short)f2bf(a.w);
  v[4] = (short)f2bf(b.x); v[5] = (short)f2bf(b.y);
  v[6] = (short)f2bf(b.z); v[7] = (short)f2bf(b.w);
  *(s16x8*)(out + i) = v;
}

// ------- kernel 2: transpose+cvt. mats 0-3 (g/u) -> interleaved GU with
// 128-row blocking: GU row = (f>>7)*256 + t*128 + (f&127), t=0 gate, 1 up.
// mats 4,5 plain transpose.
__global__ __launch_bounds__(256) void transpose_cvt_kernel(
    const float* __restrict__ in0, const float* __restrict__ in1,
    const float* __restrict__ in2, const float* __restrict__ in3,
    const float* __restrict__ in4, const float* __restrict__ in5,
    u16* __restrict__ o01, u16* __restrict__ o23,
    u16* __restrict__ o4, u16* __restrict__ o5) {
  __shared__ float s[64 * 65];
  const int mat = blockIdx.y;
  const float* in; u16* out;
  switch (mat) {
    case 0: in = in0; out = o01; break;
    case 1: in = in1; out = o01; break;
    case 2: in = in2; out = o23; break;
    case 3: in = in3; out = o23; break;
    case 4: in = in4; out = o4; break;
    default: in = in5; out = o5; break;
  }
  const int R = (mat < 4) ? 4096 : 11008;
  const int C = (mat < 4) ? 11008 : 4096;
  const int nTc = C >> 6;
  const int tr = blockIdx.x / nTc, tc = blockIdx.x - tr * nTc;
  const int r0 = tr << 6, c0 = tc << 6;
  const int t = threadIdx.x;
#pragma unroll
  for (int p = 0; p < 4; ++p) {
    const int lr = p * 16 + (t >> 4);
    const int lc = (t & 15) * 4;
    float4 v = *(const float4*)(in + (size_t)(r0 + lr) * C + (c0 + lc));
    float* sp = &s[lr * 65 + lc];
    sp[0] = v.x; sp[1] = v.y; sp[2] = v.z; sp[3] = v.w;
  }
  __syncthreads();
#pragma unroll
  for (int q = 0; q < 2; ++q) {
    const int oc = q * 32 + (t >> 3);
    const int orr = (t & 7) * 8;
    s16x8 v;
#pragma unroll
    for (int i = 0; i < 8; ++i) v[i] = (short)f2bf(s[(orr + i) * 65 + oc]);
    const int f = c0 + oc;
    size_t orow;
    if (mat < 4) orow = (size_t)((f >> 7) << 8) + ((mat & 1) << 7) + (f & 127);
    else         orow = (size_t)f;
    *(s16x8*)(out + orow * R + (r0 + orr)) = v;
  }
}

// ======== 256x256 GEMM core: 32x32x16 MFMA, 3-phase/1-barrier K-tile ========
// 8 waves (2M x 4N). Frag-once ds_reads; bf[2] n-sets resident across phases.
// LDS [2buf][2half][128][64] u16/operand; swizzle chunk = logical ^ (r&7) ^
// ((r>>3)&3) (pre-swizzled global src + read addr) — conflict-free for the
// 32x32 read pattern (verified round 7: SQ_LDS_BANK_CONFLICT = 0).
// Per K-tile T (d=T&1): Q1{rd A0,B0(d); stg A1'(T+1)->nd; lgkm0; MFMA(0,0); bar}
//   Q2{rd B1(d); stg A0',B0'(T+2)->d; lgkm0; MFMA(0,1); bar}
//   Q3{rd A1(d); stg B1'(T+2)->d; lgkm0; MFMA(1,1); MFMA(1,0); vmcnt(6); bar}
// Single barrier/phase is WAR-safe: each wave's lgkmcnt(0) completes its reads
// before it enters the phase-end barrier; stages issue only after that barrier.
// vmcnt(6) at Q3 drains exactly tile T+1's 4 halves (14->6 outstanding).
#define SBAR() __builtin_amdgcn_s_barrier()
#define LGKM0() asm volatile("s_waitcnt lgkmcnt(0)")
#define VMCNT6() asm volatile("s_waitcnt vmcnt(6)")
#define VMCNT0() asm volatile("s_waitcnt vmcnt(0)")

#define LDA(d, mh)                                                             \
  do {                                                                         \
    _Pragma("unroll") for (int fj = 0; fj < 2; ++fj)                           \
        _Pragma("unroll") for (int ks = 0; ks < 4; ++ks)                       \
        af[fj][ks] = *(const s16x8*)(ldsA + (d) * 32768 + (mh) * 16384 +       \
                                     arow + fj * 4096 + cx[ks]);               \
  } while (0)
#define LDB(d, nh)                                                             \
  do {                                                                         \
    _Pragma("unroll") for (int ks = 0; ks < 4; ++ks)                           \
        bf[nh][ks] = *(const s16x8*)(ldsB + (d) * 32768 + (nh) * 16384 +       \
                                     brow + cx[ks]);                           \
  } while (0)
#define MFMA8(mh, nh)                                                          \
  do {                                                                         \
    __builtin_amdgcn_s_setprio(1);                                             \
    _Pragma("unroll") for (int fj = 0; fj < 2; ++fj)                           \
        _Pragma("unroll") for (int ks = 0; ks < 4; ++ks)                       \
        acc[mh][fj][nh] = __builtin_amdgcn_mfma_f32_32x32x16_bf16(             \
            af[fj][ks], bf[nh][ks], acc[mh][fj][nh], 0, 0, 0);                 \
    __builtin_amdgcn_s_setprio(0);                                             \
  } while (0)

// Generic 3-phase pipeline; STG_A/STG_B are kernel-local (q = flat K-tile idx).
// HOOK runs after Q3's barrier each K-tile (epilogue insertion point).
#define GEMM_PIPE3(FKv, HOOK)                                                  \
  do {                                                                         \
    STG_A(0, 0, 0); STG_B(0, 0, 0); STG_B(0, 1, 0); STG_A(0, 1, 0);            \
    STG_A(1, 0, 1); STG_B(1, 0, 1); STG_B(1, 1, 1);                            \
    VMCNT6(); SBAR();                                                          \
    for (int T = 0; T < (FKv)-2; ++T) {                                        \
      const int d = T & 1, nd = d ^ 1;                                         \
      LDA(d, 0); LDB(d, 0);                                                    \
      STG_A(nd, 1, T + 1);                                                     \
      LGKM0(); MFMA8(0, 0); SBAR();                                            \
      LDB(d, 1);                                                               \
      STG_A(d, 0, T + 2); STG_B(d, 0, T + 2);                                  \
      LGKM0(); MFMA8(0, 1); SBAR();                                            \
      LDA(d, 1);                                                               \
      STG_B(d, 1, T + 2);                                                      \
      LGKM0(); MFMA8(1, 1); MFMA8(1, 0);                                       \
      VMCNT6(); SBAR();                                                        \
      HOOK;                                                                    \
    }                                                                          \
    LDA(0, 0); LDB(0, 0);                                                      \
    STG_A(1, 1, (FKv)-1);                                                      \
    LGKM0(); MFMA8(0, 0); SBAR();                                              \
    LDB(0, 1);                                                                 \
    LGKM0(); MFMA8(0, 1); SBAR();                                              \
    LDA(0, 1);                                                                 \
    LGKM0(); MFMA8(1, 1); MFMA8(1, 0);                                         \
    VMCNT0(); SBAR();                                                          \
    LDA(1, 0); LDB(1, 0);                                                      \
    LGKM0(); MFMA8(0, 0); SBAR();                                              \
    LDB(1, 1);                                                                 \
    LGKM0(); MFMA8(0, 1); SBAR();                                              \
    LDA(1, 1);                                                                 \
    LGKM0(); MFMA8(1, 1); MFMA8(1, 0);                                         \
  } while (0)

#define ZERO_ACC()                                                             \
  do {                                                                         \
    _Pragma("unroll") for (int a = 0; a < 2; ++a)                              \
        _Pragma("unroll") for (int b = 0; b < 2; ++b)                          \
        _Pragma("unroll") for (int c2 = 0; c2 < 2; ++c2)                       \
        _Pragma("unroll") for (int r = 0; r < 16; ++r) acc[a][b][c2][r] = 0.f; \
  } while (0)

// ---------------- persistent gate+up GEMM + silu (static XCD-aligned) -------
// c-lane = ((bid>>7)<<3)|(bid&7): the 16 blocks sharing a B-panel all have the
// same bid%8 -> same XCD -> B fetched ~once per XCD L2 (round-5 locality).
// mT pinned per block -> A-panel L2-resident. Seamless flat-K walk over
// ntiles output tiles (nT = c + 16*j).
__global__ __launch_bounds__(512, 1) void gemm_gateup_persist(
    const u16* __restrict__ A, const u16* __restrict__ GUl,
    const u16* __restrict__ GUv, const int* __restrict__ tt,
    u16* __restrict__ H) {
  __shared__ u16 sA[2][2][128][64];
  __shared__ u16 sB[2][2][128][64];

  const int bid = blockIdx.x;
  const int c = ((bid >> 7) << 3) | (bid & 7);
  const int mT = (bid >> 3) & 15;
  const int ntiles = (c < 6) ? 6 : 5;
  const int FK = ntiles * 64;

  const int t = threadIdx.x;
  const int lane = t & 63;
  const int l31 = lane & 31;
  const int kg = lane >> 5;
  const int wn = (t >> 6) & 3;
  const int wm = (t >> 8) & 1;

  const int side = tt[mT << 8];
  const u16* GU = side ? GUl : GUv;

  const int rowq = t >> 3;
  const int gsw = ((t & 7) ^ (rowq & 7) ^ ((rowq >> 3) & 3)) << 4;
  const char* srcA = (const char*)A + (size_t)(mT * 256 + rowq) * 8192 + gsw;
  const char* srcB0 = (const char*)GU + ((size_t)(c * 256) + rowq) * 8192 + gsw;
  char* ldsA = (char*)&sA[0][0][0][0];
  char* ldsB = (char*)&sB[0][0][0][0];
  const int woff = (t & 448) << 4;

#define STG_A(d, h, q)                                                         \
  do {                                                                         \
    const char* _pa = srcA + ((q)&63) * 128;                                   \
    GLOAD16(_pa + (size_t)((h)*128) * 8192,                                    \
            ldsA + (d)*32768 + (h)*16384 + woff);                              \
    GLOAD16(_pa + (size_t)((h)*128 + 64) * 8192,                               \
            ldsA + (d)*32768 + (h)*16384 + 8192 + woff);                       \
  } while (0)
#define STG_B(d, h, q)                                                         \
  do {                                                                         \
    const char* _pb = srcB0 + (size_t)((q) >> 6) * 33554432 +                  \
                      (size_t)((h)*128) * 8192 + ((q)&63) * 128;               \
    GLOAD16(_pb, ldsB + (d)*32768 + (h)*16384 + woff);                         \
    GLOAD16(_pb + (size_t)64 * 8192,                                           \
            ldsB + (d)*32768 + (h)*16384 + 8192 + woff);                       \
  } while (0)

  const int arow = (wm * 64 + l31) * 128;
  const int brow = (wn * 32 + l31) * 128;
  int cx[4];
#pragma unroll
  for (int ks = 0; ks < 4; ++ks)
    cx[ks] = ((2 * ks + kg) ^ (l31 & 7) ^ ((l31 >> 3) & 3)) << 4;

  s16x8 af[2][4], bf[2][4];
  f32x16 acc[2][2][2];
  ZERO_ACC();

#define GU_EPI(nTv)                                                            \
  do {                                                                         \
    const int _nT = (nTv);                                                     \
    const int f = _nT * 128 + wn * 32 + l31;                                   \
    _Pragma("unroll") for (int mh = 0; mh < 2; ++mh)                           \
        _Pragma("unroll") for (int fj = 0; fj < 2; ++fj) {                     \
      const int rowbase = mT * 256 + mh * 128 + wm * 64 + fj * 32 + 4 * kg;    \
      _Pragma("unroll") for (int r = 0; r < 16; ++r) {                         \
        const int row = rowbase + (r & 3) + 8 * (r >> 2);                      \
        const float gv = acc[mh][fj][0][r];                                    \
        const float uv = acc[mh][fj][1][r];                                    \
        const float hv = gv / (1.f + __expf(-gv)) * uv;                        \
        H[(size_t)row * 11008 + f] = f2bf(hv);                                 \
      }                                                                        \
    }                                                                          \
  } while (0)

  GEMM_PIPE3(FK, if ((T & 63) == 63) { GU_EPI(c + 16 * (T >> 6)); ZERO_ACC(); });
  GU_EPI(c + 16 * (ntiles - 1));
#undef STG_A
#undef STG_B
#undef GU_EPI
}

// ---------------- down GEMM (static 1 tile/block, 3-phase core) -------------
__global__ __launch_bounds__(512, 1) void gemm_down(
    const u16* __restrict__ Hm, const u16* __restrict__ Dl,
    const u16* __restrict__ Dv, const int* __restrict__ tt,
    float* __restrict__ O) {
  constexpr int KB = 22016;  // bytes per K-row
  __shared__ u16 sA[2][2][128][64];
  __shared__ u16 sB[2][2][128][64];

  const int bid = blockIdx.x;
  const int wg = (bid & 7) * 32 + (bid >> 3);  // bijective XCD swizzle
  const int mT = wg & 15;
  const int nT = wg >> 4;

  const int t = threadIdx.x;
  const int lane = t & 63;
  const int l31 = lane & 31;
  const int kg = lane >> 5;
  const int wn = (t >> 6) & 3;
  const int wm = (t >> 8) & 1;

  const int side = tt[mT << 8];
  const u16* B = side ? Dl : Dv;

  const int rowq = t >> 3;
  const int gsw = ((t & 7) ^ (rowq & 7) ^ ((rowq >> 3) & 3)) << 4;
  const char* srcA = (const char*)Hm + (size_t)(mT * 256 + rowq) * KB + gsw;
  const char* srcB = (const char*)B + (size_t)(nT * 256 + rowq) * KB + gsw;
  char* ldsA = (char*)&sA[0][0][0][0];
  char* ldsB = (char*)&sB[0][0][0][0];
  const int woff = (t & 448) << 4;

#define STG_A(d, h, q)                                                         \
  do {                                                                         \
    GLOAD16(srcA + (size_t)((h)*128) * KB + (size_t)(q)*128,                   \
            ldsA + (d)*32768 + (h)*16384 + woff);                              \
    GLOAD16(srcA + (size_t)((h)*128 + 64) * KB + (size_t)(q)*128,              \
            ldsA + (d)*32768 + (h)*16384 + 8192 + woff);                       \
  } while (0)
#define STG_B(d, h, q)                                                         \
  do {                                                                         \
    GLOAD16(srcB + (size_t)((h)*128) * KB + (size_t)(q)*128,                   \
            ldsB + (d)*32768 + (h)*16384 + woff);                              \
    GLOAD16(srcB + (size_t)((h)*128 + 64) * KB + (size_t)(q)*128,              \
            ldsB + (d)*32768 + (h)*16384 + 8192 + woff);                       \
  } while (0)

  const int arow = (wm * 64 + l31) * 128;
  const int brow = (wn * 32 + l31) * 128;
  int cx[4];
#pragma unroll
  for (int ks = 0; ks < 4; ++ks)
    cx[ks] = ((2 * ks + kg) ^ (l31 & 7) ^ ((l31 >> 3) & 3)) << 4;

  s16x8 af[2][4], bf[2][4];
  f32x16 acc[2][2][2];
  ZERO_ACC();

  GEMM_PIPE3(172, ;);

#pragma unroll
  for (int mh = 0; mh < 2; ++mh)
#pragma unroll
    for (int fj = 0; fj < 2; ++fj) {
      const int rowbase = mT * 256 + mh * 128 + wm * 64 + fj * 32 + 4 * kg;
#pragma unroll
      for (int nh = 0; nh < 2; ++nh) {
        const int col = nT * 256 + nh * 128 + wn * 32 + l31;
#pragma unroll
        for (int r = 0; r < 16; ++r) {
          const int row = rowbase + (r & 3) + 8 * (r >> 2);
          O[(size_t)row * 4096 + col] = acc[mh][fj][nh][r];
        }
      }
    }
#undef STG_A
#undef STG_B
}

extern "C" void kernel_launch(void* const* d_in, const int* in_sizes, int n_in,
                              void* d_out, int out_size, void* d_ws, size_t ws_size,
                              hipStream_t stream) {
  (void)in_sizes; (void)n_in; (void)out_size; (void)ws_size;
  const float* x  = (const float*)d_in[0];
  const int*   tt = (const int*)d_in[1];
  const float* lg = (const float*)d_in[2];
  const float* lu = (const float*)d_in[3];
  const float* ld = (const float*)d_in[4];
  const float* vg = (const float*)d_in[5];
  const float* vu = (const float*)d_in[6];
  const float* vd = (const float*)d_in[7];

  u16* ws  = (u16*)d_ws;
  u16* xbf = ws;                        // 4096*4096            = 16,777,216
  u16* GUl = xbf + 16777216;            // 22016*4096           = 90,177,536
  u16* GUv = GUl + 90177536;
  u16* ldT = GUv + 90177536;            // 4096*11008           = 45,088,768
  u16* vdT = ldT + 45088768;
  u16* hbuf = vdT + 45088768;           // 4096*11008
  // total: 332,398,592 u16 = ~665 MB

  cvt_x_kernel<<<dim3(8192), dim3(256), 0, stream>>>(x, xbf);
  transpose_cvt_kernel<<<dim3(11008, 6), dim3(256), 0, stream>>>(
      lg, lu, vg, vu, ld, vd, GUl, GUv, ldT, vdT);
  gemm_gateup_persist<<<dim3(256), dim3(512), 0, stream>>>(
      xbf, GUl, GUv, tt, hbuf);
  gemm_down<<<dim3(256), dim3(512), 0, stream>>>(hbuf, ldT, vdT, tt, (float*)d_out);
}